// Round 10
// baseline (2884.674 us; speedup 1.0000x reference)
//
#include <hip/hip_runtime.h>
#include <math.h>

#define LOG2E 1.4426950408889634f
#define LN2   0.6931471805599453f

typedef short    short8  __attribute__((ext_vector_type(8)));
typedef float    floatx4 __attribute__((ext_vector_type(4)));
typedef _Float16 half8   __attribute__((ext_vector_type(8)));

__constant__ int c_pi[28] = {0,0,0,0,0,0,0,1,1,1,1,1,1,2,2,2,2,2,3,3,3,3,4,4,4,5,5,6};
__constant__ int c_pj[28] = {1,2,3,4,5,6,7,2,3,4,5,6,7,3,4,5,6,7,4,5,6,7,5,6,7,6,7,7};

// ---------------- static device storage ----------------
__device__ unsigned short g_cellsL[16*256*256];   // bf16 bits, gathered local cells
__device__ unsigned short g_cellsG[8*512*256];    // bf16 bits, gathered global cells
__device__ float g_x2L[16*256];
__device__ float g_x2G[8*512];
__device__ int   g_idxL[16*256];
__device__ int   g_idxG[8*512];
// fp16 cost matrices, no transposes. Local: [0,56)=Cxy, [56,72)=Cxx. 9.4 MB
__device__ _Float16 g_CL[72*256*256];
// Global: [0,28)=Cxy, [28,36)=Cxx. 18.9 MB
__device__ _Float16 g_CG[36*512*512];
// cross-slice exchange: role-2 col partials (3-deep pipeline buffer),
// role-3 px slices (2-deep)
__device__ unsigned long long g_xch[28][3][4][512]; // packed (m,s)
__device__ float g_xpx[8][2][4][128];
__device__ unsigned g_flag[36][4][16];              // round-tagged flags, 64B apart
__device__ float g_acc[4];                          // SL, PL, SG, PG
__device__ float g_efT[122], g_ivT[122];            // eps schedule table

// ---------------- helpers ----------------
__device__ __forceinline__ unsigned short f2bf(float f) {
    unsigned u = __float_as_uint(f);
    u += 0x7fffu + ((u >> 16) & 1u);              // RNE; inputs are finite
    return (unsigned short)(u >> 16);
}
// relaxed agent-scope (cross-XCD coherent, no cache-maintenance)
__device__ __forceinline__ void xst64(unsigned long long* p, unsigned long long v) {
    __hip_atomic_store(p, v, __ATOMIC_RELAXED, __HIP_MEMORY_SCOPE_AGENT);
}
__device__ __forceinline__ unsigned long long xld64(const unsigned long long* p) {
    return __hip_atomic_load(p, __ATOMIC_RELAXED, __HIP_MEMORY_SCOPE_AGENT);
}
__device__ __forceinline__ void xstf(float* p, float v) {
    __hip_atomic_store(p, v, __ATOMIC_RELAXED, __HIP_MEMORY_SCOPE_AGENT);
}
__device__ __forceinline__ float xldf(const float* p) {
    return __hip_atomic_load(p, __ATOMIC_RELAXED, __HIP_MEMORY_SCOPE_AGENT);
}
__device__ __forceinline__ void flag_set(int gid, int q, unsigned v) {
    __hip_atomic_store(&g_flag[gid][q][0], v, __ATOMIC_RELAXED, __HIP_MEMORY_SCOPE_AGENT);
}
__device__ __forceinline__ unsigned flag_get(int gid, int q) {
    return __hip_atomic_load(&g_flag[gid][q][0], __ATOMIC_RELAXED, __HIP_MEMORY_SCOPE_AGENT);
}
// poll all 4 slice flags >= tgt (thread 0), then block barrier
__device__ __forceinline__ void flag_wait4(int gid, unsigned tgt) {
    if (threadIdx.x == 0) {
        int guard = 0;
        for (;;) {
            unsigned a = flag_get(gid, 0), b = flag_get(gid, 1);
            unsigned c = flag_get(gid, 2), d = flag_get(gid, 3);
            if (a >= tgt && b >= tgt && c >= tgt && d >= tgt) break;
            __builtin_amdgcn_s_sleep(1);
            if (++guard > 20000000) break;        // failsafe: never hang
        }
    }
    __syncthreads();
}

// ---------------- index lists ----------------
__global__ void k_index(const int* __restrict__ labels, const int* __restrict__ subg) {
    int b = blockIdx.x, lane = threadIdx.x;       // 24 blocks x 64 threads
    int want_l, want_s, cap; int* out;
    if (b < 16) { want_l = b >> 3; want_s = b & 7; cap = 256; out = g_idxL + b*256; }
    else        { want_l = -1;     want_s = b - 16; cap = 512; out = g_idxG + (b-16)*512; }
    int cnt = 0;
    for (int base = 0; base < 4096; base += 64) {
        int i = base + lane;
        bool m = (subg[i] == want_s) && (want_l < 0 || labels[i] == want_l);
        unsigned long long mask = __ballot(m);
        int pos = cnt + __popcll(mask & ((1ull << lane) - 1ull));
        if (m && pos < cap) out[pos] = i;
        cnt += __popcll(mask);
    }
}

// ---------------- gather rows -> bf16 cells + fp32 sq-norms -----------------
__global__ void k_gather(const float* __restrict__ feat) {
    int wv = blockIdx.x*4 + (threadIdx.x >> 6);   // 8192 waves, one row each
    int lane = threadIdx.x & 63;
    const float* src; unsigned short* dst; float* x2out;
    if (wv < 4096) {
        int c = wv >> 8, row = wv & 255;
        src = feat + (size_t)g_idxL[c*256+row]*256;
        dst = g_cellsL + (size_t)(c*256+row)*256;
        x2out = g_x2L + c*256 + row;
    } else {
        int v = wv - 4096; int c = v >> 9, row = v & 511;
        src = feat + (size_t)g_idxG[c*512+row]*256;
        dst = g_cellsG + (size_t)(c*512+row)*256;
        x2out = g_x2G + c*512 + row;
    }
    floatx4 v4 = *(const floatx4*)(src + lane*4);
    float s = v4[0]*v4[0] + v4[1]*v4[1] + v4[2]*v4[2] + v4[3]*v4[3];
    unsigned lo = (unsigned)f2bf(v4[0]) | ((unsigned)f2bf(v4[1]) << 16);
    unsigned hi = (unsigned)f2bf(v4[2]) | ((unsigned)f2bf(v4[3]) << 16);
    unsigned* d32 = (unsigned*)dst;
    d32[lane*2] = lo; d32[lane*2+1] = hi;
    for (int o = 32; o; o >>= 1) s += __shfl_xor(s, o);
    if (lane == 0) *x2out = s;
}

// ---------------- cost matrices via bf16 MFMA (no transposes) ---------------
__global__ void k_gemm() {
    int job = blockIdx.x*4 + (threadIdx.x >> 6);
    int lane = threadIdx.x & 63;
    const unsigned short *A, *B; _Float16* Cout; const float *x2a, *x2b;
    int m, ti, tj;
    if (job < 18432) {                            // local: 72 matrices x 256 tiles
        int mm = job >> 8, t = job & 255; ti = t >> 4; tj = t & 15; m = 256;
        int ca, cb;
        if (mm < 56) { int lbl = mm/28, q = mm%28; ca = lbl*8 + c_pi[q]; cb = lbl*8 + c_pj[q]; }
        else         { int c = mm-56; ca = cb = c; }
        A = g_cellsL + (size_t)ca*65536; B = g_cellsL + (size_t)cb*65536;
        x2a = g_x2L + ca*256; x2b = g_x2L + cb*256;
        Cout = g_CL + (size_t)mm*65536;
    } else {                                      // global: 36 matrices x 1024 tiles
        int jj = job - 18432; int mm = jj >> 10, t = jj & 1023; ti = t >> 5; tj = t & 31; m = 512;
        int ca, cb;
        if (mm < 28) { ca = c_pi[mm]; cb = c_pj[mm]; }
        else         { ca = cb = mm-28; }
        A = g_cellsG + (size_t)ca*131072; B = g_cellsG + (size_t)cb*131072;
        x2a = g_x2G + ca*512; x2b = g_x2G + cb*512;
        Cout = g_CG + (size_t)mm*262144;
    }
    int r = lane & 15, quad = lane >> 4;
    const unsigned short* Ap = A + (size_t)(ti*16 + r)*256 + quad*8;
    const unsigned short* Bp = B + (size_t)(tj*16 + r)*256 + quad*8;
    floatx4 acc = {0.f, 0.f, 0.f, 0.f};
    #pragma unroll
    for (int k = 0; k < 256; k += 32) {
        short8 av = *(const short8*)(Ap + k);
        short8 bv = *(const short8*)(Bp + k);
        acc = __builtin_amdgcn_mfma_f32_16x16x32_bf16(av, bv, acc, 0, 0, 0);
    }
    int jc = tj*16 + r;                           // D: col = lane&15, row = quad*4 + reg
    float y2 = x2b[jc];
    #pragma unroll
    for (int rr = 0; rr < 4; rr++) {
        int ir = ti*16 + quad*4 + rr;
        float v = x2a[ir] + y2 - 2.f*acc[rr];
        Cout[(size_t)ir*m + jc] = (_Float16)(0.5f*fmaxf(v, 0.f));
    }
}

// ---------------- init: flags, accumulators, eps table ----------------------
__global__ void k_init() {
    int t = threadIdx.x;                          // 144 threads
    if (t < 144) g_flag[t >> 2][t & 3][0] = 0u;
    if (t < 4)  g_acc[t] = 0.f;
    if (t < 122) {                                // same double math as reference
        double e = 1024.0 * pow(0.81, (double)t);
        if (e < 1e-8) e = 1e-8;
        g_efT[t] = (float)e;
        g_ivT[t] = (float)(1.0/e);
    }
}

// ---------------- persistent solver: C LDS-resident, 123 rounds -------------
// 216 blocks x 512 thr, 152 KB LDS, 1 block/CU -> all co-resident.
// Role 2 (global pair slice) pipeline per iteration k:
//   B_k: f_{k+1} = row-sweep(g_k)                (local)
//   A_{k+1}: col partials from f_{k+1}, eps_{k+1} -> store buf (k+1)%3, flag k+2
//   C_k: poll flags>=k+1, read buf k%3, combine -> g_{k+1}
// (A before C puts ~4-5us of compute inside the sync shadow; 3-deep buffer is
//  race-free: partner's A_k flag implies its C_{k-2} loads drained.)
extern __shared__ char smem[];
__global__ void __launch_bounds__(512) k_solve() {
    _Float16* sC = (_Float16*)smem;               // 131072 B
    float* scr  = (float*)(smem + 131072);        // 16384 B (role 0 tree)
    float* sg   = (float*)(smem + 147456);        // [2][512]
    float* sf   = (float*)(smem + 151552);        // [2][512] (role2 uses [2][128])
    float* sred = (float*)(smem + 155648);        // 8 floats
    int b = blockIdx.x, tid = threadIdx.x, lane = tid & 63, w = tid >> 6;

    int role, gid = -1, q = 0;
    const _Float16* Csrc; float loga;
    if (b < 112)      { role = 2; gid = b >> 2; q = b & 3;
                        Csrc = g_CG + (size_t)gid*262144 + (size_t)q*65536;
                        loga = -6.238324625039508f; }
    else if (b < 144) { role = 3; int t = b - 112; int c = t >> 2; q = t & 3; gid = 28 + c;
                        Csrc = g_CG + (size_t)(28+c)*262144 + (size_t)q*65536;
                        loga = -6.238324625039508f; }
    else if (b < 200) { role = 0; int p = b - 144;
                        Csrc = g_CL + (size_t)p*65536;
                        loga = -5.545177444479562f; }
    else              { role = 1; int c = b - 200;
                        Csrc = g_CL + (size_t)(56+c)*65536;
                        loga = -5.545177444479562f; }

    // ---- stage C into LDS (once), zero potentials ----
    for (int i = tid; i < 8192; i += 512)
        ((floatx4*)sC)[i] = ((const floatx4*)Csrc)[i];
    for (int i = tid; i < 1024; i += 512) { sg[i] = 0.f; sf[i] = 0.f; }
    __syncthreads();

    // role-2 col-sweep phase: partials for round j (uses f_j, eps_j)
    auto a_phase = [&](int j) {
        int ei = (j < 122) ? j : 121;
        float efa = g_efT[ei];
        float iva = g_ivT[ei];
        int hd = (efa < 1e-5f) ? 1 : 0;
        float i2a = iva * LOG2E;
        float lg2a = loga * LOG2E;
        const float* fsrc = sf + (j & 1)*128;
        __syncthreads();                          // f_j was lane-0-scattered
        float m2 = -3.4e38f, ss = 0.f;
        const _Float16* cp = sC + tid;            // lane owns column tid
        if (!hd) {
            #pragma unroll 4
            for (int r = 0; r < 128; r++) {
                float a2 = lg2a + fsrc[r]*i2a;
                float u  = a2 - (float)cp[(size_t)r*512]*i2a;
                float mn = fmaxf(m2, u);
                ss = ss*exp2f(m2-mn) + exp2f(u-mn);
                m2 = mn;
            }
        } else {
            #pragma unroll 8
            for (int r = 0; r < 128; r++) {
                float a2 = lg2a + fsrc[r]*i2a;
                m2 = fmaxf(m2, a2 - (float)cp[(size_t)r*512]*i2a);
            }
        }
        xst64(&g_xch[gid][j%3][q][tid],
              (unsigned long long)__float_as_uint(m2) |
              ((unsigned long long)__float_as_uint(ss) << 32));
        asm volatile("s_waitcnt vmcnt(0)" ::: "memory");
        __syncthreads();
        if (tid == 0) flag_set(gid, q, (unsigned)(j+1));
    };

    if (role == 2) a_phase(0);                    // prologue: partials from f_0=0

    int po = 0;
    for (int round = 0; round < 123; round++) {
        int fin = (round == 122);
        int ei = fin ? 121 : round;
        float ef  = g_efT[ei];
        float inv = g_ivT[ei];
        int hard = (ef < 1e-5f) ? 1 : 0;
        float i2  = inv * LOG2E;
        float lg2 = loga * LOG2E;
        float meps = -ef * LN2;
        int pn = po ^ 1;

        if (role == 2) {                          // ---- global pair slice ----
            // ---- B: row sweep (uses g_k) -> f_{k+1} ------------------------
            {
                const float* gp = sg + po*512;
                const float* fpo = sf + po*128;
                float* fpn = sf + pn*128;
                float h2[8];
                #pragma unroll
                for (int k = 0; k < 8; k++) h2[k] = lg2 + gp[lane*8+k]*i2;
                #pragma unroll 4
                for (int s = 0; s < 16; s++) {
                    int r = w*16 + s;
                    half8 cv = *(const half8*)(sC + (size_t)r*512 + lane*8);
                    float tv[8]; float mx = -3.4e38f;
                    #pragma unroll
                    for (int k = 0; k < 8; k++) {
                        float t = h2[k] - (float)cv[k]*i2;
                        tv[k] = t; mx = fmaxf(mx, t);
                    }
                    #pragma unroll
                    for (int o = 32; o; o >>= 1) mx = fmaxf(mx, __shfl_xor(mx, o));
                    float ft;
                    if (!hard) {
                        float sum = 0.f;
                        #pragma unroll
                        for (int k = 0; k < 8; k++) sum += exp2f(tv[k]-mx);
                        #pragma unroll
                        for (int o = 32; o; o >>= 1) sum += __shfl_xor(sum, o);
                        ft = meps*(mx + __log2f(sum));
                    } else ft = meps*mx;
                    if (lane == 0) fpn[r] = fin ? ft : 0.5f*(fpo[r] + ft);
                }
            }
            // ---- A(k+1): next round's col partials (inside sync shadow) ----
            if (!fin) a_phase(round + 1);
            // ---- C: poll, read buf k%3, combine -> g_{k+1} -----------------
            flag_wait4(gid, (unsigned)(round + 1));
            {
                int rb = round % 3;
                int c = tid;
                unsigned long long v0 = xld64(&g_xch[gid][rb][0][c]);
                unsigned long long v1 = xld64(&g_xch[gid][rb][1][c]);
                unsigned long long v2 = xld64(&g_xch[gid][rb][2][c]);
                unsigned long long v3 = xld64(&g_xch[gid][rb][3][c]);
                float a0 = __uint_as_float((unsigned)v0), b0 = __uint_as_float((unsigned)(v0 >> 32));
                float a1 = __uint_as_float((unsigned)v1), b1 = __uint_as_float((unsigned)(v1 >> 32));
                float a2m = __uint_as_float((unsigned)v2), b2 = __uint_as_float((unsigned)(v2 >> 32));
                float a3 = __uint_as_float((unsigned)v3), b3 = __uint_as_float((unsigned)(v3 >> 32));
                float m = fmaxf(fmaxf(a0, a1), fmaxf(a2m, a3));
                float gt;
                if (!hard) {
                    float s = b0*exp2f(a0-m) + b1*exp2f(a1-m) + b2*exp2f(a2m-m) + b3*exp2f(a3-m);
                    gt = meps*(m + __log2f(s));
                } else gt = meps*m;
                sg[pn*512+c] = fin ? gt : 0.5f*(sg[po*512+c] + gt);
            }
            __syncthreads();
        } else if (role == 3) {                   // ---- global Cxx slice ----
            const float* pp = sg + po*512;
            int rb = round & 1;
            float h2[8];
            #pragma unroll
            for (int k = 0; k < 8; k++) h2[k] = lg2 + pp[lane*8+k]*i2;
            int gx = gid - 28;
            #pragma unroll 4
            for (int s = 0; s < 16; s++) {
                int r = w*16 + s;
                half8 cv = *(const half8*)(sC + (size_t)r*512 + lane*8);
                float tv[8]; float mx = -3.4e38f;
                #pragma unroll
                for (int k = 0; k < 8; k++) {
                    float t = h2[k] - (float)cv[k]*i2;
                    tv[k] = t; mx = fmaxf(mx, t);
                }
                #pragma unroll
                for (int o = 32; o; o >>= 1) mx = fmaxf(mx, __shfl_xor(mx, o));
                float ft;
                if (!hard) {
                    float sum = 0.f;
                    #pragma unroll
                    for (int k = 0; k < 8; k++) sum += exp2f(tv[k]-mx);
                    #pragma unroll
                    for (int o = 32; o; o >>= 1) sum += __shfl_xor(sum, o);
                    ft = meps*(mx + __log2f(sum));
                } else ft = meps*mx;
                if (lane == 0) {
                    float old = pp[q*128 + r];
                    xstf(&g_xpx[gx][rb][q][r], fin ? ft : 0.5f*(old + ft));
                }
            }
            asm volatile("s_waitcnt vmcnt(0)" ::: "memory");
            __syncthreads();
            if (tid == 0) flag_set(gid, q, (unsigned)(round + 1));
            flag_wait4(gid, (unsigned)(round + 1));
            { int c = tid; sg[pn*512+c] = xldf(&g_xpx[gx][rb][c>>7][c&127]); }
            __syncthreads();
        } else if (role == 0) {                   // ---- local pair (private) ----
            const float* gp = sg + po*512;
            const float* fpo = sf + po*512;
            float* fpn = sf + pn*512;
            int co = lane & 31, radd = lane >> 5;
            float h2[8];
            #pragma unroll
            for (int k = 0; k < 8; k++) h2[k] = lg2 + gp[co*8+k]*i2;
            float m2[8], ssv[8];
            #pragma unroll
            for (int k = 0; k < 8; k++) { m2[k] = -3.4e38f; ssv[k] = 0.f; }
            #pragma unroll 4
            for (int s = 0; s < 16; s++) {
                int row = w*32 + 2*s + radd;
                half8 cv = *(const half8*)(sC + row*256 + co*8);
                float fr = fpo[row];
                float a2 = lg2 + fr*i2;
                float tv[8]; float mx = -3.4e38f;
                #pragma unroll
                for (int k = 0; k < 8; k++) {
                    float d = (float)cv[k]*(-i2);
                    float t = h2[k] + d; tv[k] = t; mx = fmaxf(mx, t);
                    float u = a2 + d;
                    float mn = fmaxf(m2[k], u);
                    if (!hard) ssv[k] = ssv[k]*exp2f(m2[k]-mn) + exp2f(u-mn);
                    m2[k] = mn;
                }
                #pragma unroll
                for (int o = 16; o; o >>= 1) mx = fmaxf(mx, __shfl_xor(mx, o));
                float ft;
                if (!hard) {
                    float sum = 0.f;
                    #pragma unroll
                    for (int k = 0; k < 8; k++) sum += exp2f(tv[k]-mx);
                    #pragma unroll
                    for (int o = 16; o; o >>= 1) sum += __shfl_xor(sum, o);
                    ft = meps*(mx + __log2f(sum));
                } else ft = meps*mx;
                if ((lane & 31) == 0) fpn[row] = fin ? ft : 0.5f*(fr + ft);
            }
            #pragma unroll
            for (int k = 0; k < 8; k++) {         // merge half-waves (same cols)
                float mo = __shfl_xor(m2[k], 32), so = __shfl_xor(ssv[k], 32);
                float mn = fmaxf(m2[k], mo);
                if (!hard) ssv[k] = ssv[k]*exp2f(m2[k]-mn) + so*exp2f(mo-mn);
                m2[k] = mn;
            }
            if (w >= 4 && lane < 32) {
                float* pm = scr + (w-4)*256; float* ps = scr + 1024 + (w-4)*256;
                #pragma unroll
                for (int k = 0; k < 8; k++) { pm[co*8+k] = m2[k]; ps[co*8+k] = ssv[k]; }
            }
            __syncthreads();
            if (w < 4 && lane < 32) {
                const float* pm = scr + w*256; const float* ps = scr + 1024 + w*256;
                #pragma unroll
                for (int k = 0; k < 8; k++) {
                    float mo = pm[co*8+k], so = ps[co*8+k];
                    float mn = fmaxf(m2[k], mo);
                    if (!hard) ssv[k] = ssv[k]*exp2f(m2[k]-mn) + so*exp2f(mo-mn);
                    m2[k] = mn;
                }
            }
            __syncthreads();
            if (w >= 1 && w < 4 && lane < 32) {
                float* pm = scr + (w-1)*256; float* ps = scr + 1024 + (w-1)*256;
                #pragma unroll
                for (int k = 0; k < 8; k++) { pm[co*8+k] = m2[k]; ps[co*8+k] = ssv[k]; }
            }
            __syncthreads();
            if (w == 0 && lane < 32) {
                #pragma unroll
                for (int j = 0; j < 3; j++) {
                    const float* pm = scr + j*256; const float* ps = scr + 1024 + j*256;
                    #pragma unroll
                    for (int k = 0; k < 8; k++) {
                        float mo = pm[co*8+k], so = ps[co*8+k];
                        float mn = fmaxf(m2[k], mo);
                        if (!hard) ssv[k] = ssv[k]*exp2f(m2[k]-mn) + so*exp2f(mo-mn);
                        m2[k] = mn;
                    }
                }
                #pragma unroll
                for (int k = 0; k < 8; k++) {
                    int c = co*8 + k;
                    float gt = hard ? meps*m2[k] : meps*(m2[k] + __log2f(ssv[k]));
                    sg[pn*512+c] = fin ? gt : 0.5f*(sg[po*512+c] + gt);
                }
            }
            __syncthreads();
        } else {                                  // ---- local Cxx (private) ----
            const float* pp = sg + po*512;
            float* ppn = sg + pn*512;
            int co = lane & 31, radd = lane >> 5;
            float h2[8];
            #pragma unroll
            for (int k = 0; k < 8; k++) h2[k] = lg2 + pp[co*8+k]*i2;
            #pragma unroll 4
            for (int s = 0; s < 16; s++) {
                int row = w*32 + 2*s + radd;
                half8 cv = *(const half8*)(sC + row*256 + co*8);
                float tv[8]; float mx = -3.4e38f;
                #pragma unroll
                for (int k = 0; k < 8; k++) {
                    float t = h2[k] - (float)cv[k]*i2;
                    tv[k] = t; mx = fmaxf(mx, t);
                }
                #pragma unroll
                for (int o = 16; o; o >>= 1) mx = fmaxf(mx, __shfl_xor(mx, o));
                float ft;
                if (!hard) {
                    float sum = 0.f;
                    #pragma unroll
                    for (int k = 0; k < 8; k++) sum += exp2f(tv[k]-mx);
                    #pragma unroll
                    for (int o = 16; o; o >>= 1) sum += __shfl_xor(sum, o);
                    ft = meps*(mx + __log2f(sum));
                } else ft = meps*mx;
                if ((lane & 31) == 0) {
                    float old = pp[row];
                    ppn[row] = fin ? ft : 0.5f*(old + ft);
                }
            }
            __syncthreads();
        }
        po = pn;
    }

    // ---- final reduction: accumulate loss components ----
    float v = 0.f, v2 = 0.f; int idx, idx2 = -1;
    if (role == 0)      { if (tid < 256) v = sf[po*512+tid] + sg[po*512+tid]; idx = 0; }
    else if (role == 1) { if (tid < 256) v = sg[po*512+tid]; idx = 1; }
    else if (role == 2) { if (tid < 128) v = sf[po*128+tid]; idx = 2;
                          if (q == 0) { v2 = sg[po*512+tid]; idx2 = 2; } }
    else                { if (tid < 128) v = sg[po*512 + q*128 + tid]; idx = 3; }
    #pragma unroll
    for (int o = 32; o; o >>= 1) v += __shfl_xor(v, o);
    if ((tid & 63) == 0) sred[w] = v;
    __syncthreads();
    if (tid == 0) {
        float t = 0.f;
        #pragma unroll
        for (int i = 0; i < 8; i++) t += sred[i];
        atomicAdd(&g_acc[idx], t);
    }
    if (idx2 >= 0) {
        __syncthreads();
        #pragma unroll
        for (int o = 32; o; o >>= 1) v2 += __shfl_xor(v2, o);
        if ((tid & 63) == 0) sred[w] = v2;
        __syncthreads();
        if (tid == 0) {
            float t = 0.f;
            #pragma unroll
            for (int i = 0; i < 8; i++) t += sred[i];
            atomicAdd(&g_acc[idx2], t);
        }
    }
}

// ---------------- final combine ---------------------------------------------
__global__ void k_combine(float* __restrict__ out) {
    if (threadIdx.x == 0) {
        float SL = g_acc[0], PL = g_acc[1], SG = g_acc[2], PG = g_acc[3];
        out[0] = (SL/14336.f - PL/2048.f) + 0.5f*(SG/14336.f - PG/2048.f);
    }
}

// ---------------- host launcher ---------------------------------------------
extern "C" void kernel_launch(void* const* d_in, const int* in_sizes, int n_in,
                              void* d_out, int out_size, void* d_ws, size_t ws_size,
                              hipStream_t stream) {
    (void)in_sizes; (void)n_in; (void)out_size; (void)d_ws; (void)ws_size;
    const float* feat  = (const float*)d_in[0];
    const int* labels  = (const int*)d_in[1];
    const int* subg    = (const int*)d_in[2];

    static int attr_set = 0;
    if (!attr_set) {
        hipFuncSetAttribute((const void*)k_solve,
                            hipFuncAttributeMaxDynamicSharedMemorySize, 155712);
        attr_set = 1;
    }

    k_index <<<24,    64, 0, stream>>>(labels, subg);
    k_gather<<<2048, 256, 0, stream>>>(feat);
    k_gemm  <<<13824,256, 0, stream>>>();
    k_init  <<<1,    256, 0, stream>>>();
    k_solve <<<216,  512, 155712, stream>>>();
    k_combine<<<1,    64, 0, stream>>>((float*)d_out);
}

// Round 11
// 1905.861 us; speedup vs baseline: 1.5136x; 1.5136x over previous
//
#include <hip/hip_runtime.h>
#include <math.h>

#define LOG2E 1.4426950408889634f
#define LN2   0.6931471805599453f

typedef short    short8  __attribute__((ext_vector_type(8)));
typedef float    floatx4 __attribute__((ext_vector_type(4)));
typedef _Float16 half8   __attribute__((ext_vector_type(8)));

__constant__ int c_pi[28] = {0,0,0,0,0,0,0,1,1,1,1,1,1,2,2,2,2,2,3,3,3,3,4,4,4,5,5,6};
__constant__ int c_pj[28] = {1,2,3,4,5,6,7,2,3,4,5,6,7,3,4,5,6,7,4,5,6,7,5,6,7,6,7,7};

// ---------------- static device storage ----------------
__device__ unsigned short g_cellsL[16*256*256];   // bf16 bits, gathered local cells
__device__ unsigned short g_cellsG[8*512*256];    // bf16 bits, gathered global cells
__device__ float g_x2L[16*256];
__device__ float g_x2G[8*512];
__device__ int   g_idxL[16*256];
__device__ int   g_idxG[8*512];
// fp16 cost matrices. Local: [0,56)=Cxy, [56,112)=Cyx(T), [112,128)=Cxx. 16.8 MB
__device__ _Float16 g_CL[128*256*256];
// Global: [0,28)=Cxy, [28,56)=Cyx(T), [56,64)=Cxx. 33.6 MB
__device__ _Float16 g_CG[64*512*512];
__device__ float g_fL[2][56*256];
__device__ float g_gL[2][56*256];
__device__ float g_pxL[2][16*256];
__device__ float g_fG[2][28*512];
__device__ float g_gG[2][28*512];
__device__ float g_pxG[2][8*512];

// ---------------- helpers ----------------
__device__ __forceinline__ unsigned short f2bf(float f) {
    unsigned u = __float_as_uint(f);
    u += 0x7fffu + ((u >> 16) & 1u);          // RNE; inputs are finite
    return (unsigned short)(u >> 16);
}

// ---------------- index lists: first-m matches in order (ballot scan) -------
__global__ void k_index(const int* __restrict__ labels, const int* __restrict__ subg) {
    int b = blockIdx.x, lane = threadIdx.x;   // 24 blocks x 64 threads
    int want_l, want_s, cap; int* out;
    if (b < 16) { want_l = b >> 3; want_s = b & 7; cap = 256; out = g_idxL + b*256; }
    else        { want_l = -1;     want_s = b - 16; cap = 512; out = g_idxG + (b-16)*512; }
    int cnt = 0;
    for (int base = 0; base < 4096; base += 64) {
        int i = base + lane;
        bool m = (subg[i] == want_s) && (want_l < 0 || labels[i] == want_l);
        unsigned long long mask = __ballot(m);
        int pos = cnt + __popcll(mask & ((1ull << lane) - 1ull));
        if (m && pos < cap) out[pos] = i;
        cnt += __popcll(mask);
    }
}

// ---------------- gather rows -> bf16 cells + fp32 sq-norms -----------------
__global__ void k_gather(const float* __restrict__ feat) {
    int wv = blockIdx.x*4 + (threadIdx.x >> 6);   // 8192 waves, one row each
    int lane = threadIdx.x & 63;
    const float* src; unsigned short* dst; float* x2out;
    if (wv < 4096) {
        int c = wv >> 8, row = wv & 255;
        src = feat + (size_t)g_idxL[c*256+row]*256;
        dst = g_cellsL + (size_t)(c*256+row)*256;
        x2out = g_x2L + c*256 + row;
    } else {
        int v = wv - 4096; int c = v >> 9, row = v & 511;
        src = feat + (size_t)g_idxG[c*512+row]*256;
        dst = g_cellsG + (size_t)(c*512+row)*256;
        x2out = g_x2G + c*512 + row;
    }
    floatx4 v4 = *(const floatx4*)(src + lane*4);
    float s = v4[0]*v4[0] + v4[1]*v4[1] + v4[2]*v4[2] + v4[3]*v4[3];
    unsigned lo = (unsigned)f2bf(v4[0]) | ((unsigned)f2bf(v4[1]) << 16);
    unsigned hi = (unsigned)f2bf(v4[2]) | ((unsigned)f2bf(v4[3]) << 16);
    unsigned* d32 = (unsigned*)dst;
    d32[lane*2] = lo; d32[lane*2+1] = hi;
    for (int o = 32; o; o >>= 1) s += __shfl_xor(s, o);
    if (lane == 0) *x2out = s;
}

// ---------------- cost matrices via bf16 MFMA (wave = one 16x16 tile) -------
// C_ij = 0.5*max(x2_i + y2_j - 2*x.y, 0), stored fp16. T matrices are built as
// an independent GEMM with A/B swapped (coalesced writes, no transpose pass).
__global__ void k_gemm() {
    int job = blockIdx.x*4 + (threadIdx.x >> 6);
    int lane = threadIdx.x & 63;
    const unsigned short *A, *B; _Float16* Cout; const float *x2a, *x2b;
    int m, ti, tj;
    if (job < 32768) {                      // local: 128 matrices x 256 tiles
        int mm = job >> 8, t = job & 255; ti = t >> 4; tj = t & 15; m = 256;
        int ca, cb;
        if (mm < 56)       { int lbl = mm/28,  q = mm%28;  ca = lbl*8 + c_pi[q]; cb = lbl*8 + c_pj[q]; }
        else if (mm < 112) { int p = mm-56; int lbl = p/28, q = p%28;
                             ca = lbl*8 + c_pj[q]; cb = lbl*8 + c_pi[q]; }
        else               { int c = mm-112; ca = cb = c; }
        A = g_cellsL + (size_t)ca*65536; B = g_cellsL + (size_t)cb*65536;
        x2a = g_x2L + ca*256; x2b = g_x2L + cb*256;
        Cout = g_CL + (size_t)mm*65536;
    } else {                                // global: 64 matrices x 1024 tiles
        int jj = job - 32768; int mm = jj >> 10, t = jj & 1023; ti = t >> 5; tj = t & 31; m = 512;
        int ca, cb;
        if (mm < 28)      { ca = c_pi[mm];    cb = c_pj[mm]; }
        else if (mm < 56) { ca = c_pj[mm-28]; cb = c_pi[mm-28]; }
        else              { ca = cb = mm-56; }
        A = g_cellsG + (size_t)ca*131072; B = g_cellsG + (size_t)cb*131072;
        x2a = g_x2G + ca*512; x2b = g_x2G + cb*512;
        Cout = g_CG + (size_t)mm*262144;
    }
    int r = lane & 15, quad = lane >> 4;
    const unsigned short* Ap = A + (size_t)(ti*16 + r)*256 + quad*8;
    const unsigned short* Bp = B + (size_t)(tj*16 + r)*256 + quad*8;
    floatx4 acc = {0.f, 0.f, 0.f, 0.f};
    #pragma unroll
    for (int k = 0; k < 256; k += 32) {
        short8 av = *(const short8*)(Ap + k);
        short8 bv = *(const short8*)(Bp + k);
        acc = __builtin_amdgcn_mfma_f32_16x16x32_bf16(av, bv, acc, 0, 0, 0);
    }
    int jc = tj*16 + r;                     // D: col = lane&15, row = quad*4 + reg
    float y2 = x2b[jc];
    #pragma unroll
    for (int rr = 0; rr < 4; rr++) {
        int ir = ti*16 + quad*4 + rr;
        float v = x2a[ir] + y2 - 2.f*acc[rr];
        Cout[(size_t)ir*m + jc] = (_Float16)(0.5f*fmaxf(v, 0.f));
    }
}

// ---------------- zero the parity-0 potential buffers -----------------------
__global__ void k_init() {
    int t = blockIdx.x*256 + threadIdx.x;   // 65536 threads
    if      (t < 14336) g_fL[0][t] = 0.f;
    else if (t < 28672) g_gL[0][t-14336] = 0.f;
    else if (t < 32768) g_pxL[0][t-28672] = 0.f;
    else if (t < 47104) g_fG[0][t-32768] = 0.f;
    else if (t < 61440) g_gG[0][t-47104] = 0.f;
    else                g_pxG[0][t-61440] = 0.f;
}

// ---------------- row softmin pass, fully register-resident -----------------
// ft_i = -eps*LSE_j(h_j - C_ij/eps); every pass is a row pass (T materialized).
// M=256: half-wave per row (lanes 0-31 / 32-63), 2*STEPS rows/wave.
// M=512: full wave per row, STEPS rows/wave.
// STEPS=6 main stripes (6 KB/wave), STEPS=2 tail stripes (2 KB/wave).
// 4-deep C prefetch ring (3 loads outstanding) + upfront f_old preload:
// r6's 2-stage pipeline kept only 1 outstanding 1KB load/wave -> latency-bound.
template<int M, int STEPS>
__device__ __forceinline__ void sm_pass(const _Float16* __restrict__ C,
    const float* __restrict__ hsrc, const float* __restrict__ fold,
    float* __restrict__ fout, int r0, float eps, float inv_eps, float loga,
    int hard, int fin)
{
    const int W = (M == 256) ? 16 : 32;     // shfl butterfly start
    int tid = threadIdx.x, lane = tid & 63, w = tid >> 6;
    int co = (M == 256) ? (lane & 31) : lane;
    float h[8];
    floatx4 h0 = *(const floatx4*)(hsrc + co*8);
    floatx4 h1 = *(const floatx4*)(hsrc + co*8 + 4);
    #pragma unroll
    for (int k = 0; k < 4; k++) { h[k] = loga + h0[k]*inv_eps; h[4+k] = loga + h1[k]*inv_eps; }
    int rbase = (M == 256) ? (r0 + w*2*STEPS) : (r0 + w*STEPS);
    int rowst = (M == 256) ? 2 : 1;
    int radd  = (M == 256) ? (lane >> 5) : 0;
    bool wr   = (M == 256) ? ((lane & 31) == 0) : (lane == 0);
    int rr0 = rbase + radd;

    const _Float16* cp = C + (size_t)rr0*M + co*8;
    float fArr[STEPS];
    #pragma unroll
    for (int s = 0; s < STEPS; s++) fArr[s] = fold[rr0 + rowst*s];
    half8 cb[4];
    #pragma unroll
    for (int s = 0; s < 3; s++)
        if (s < STEPS) cb[s] = *(const half8*)(cp + (size_t)rowst*M*s);
    #pragma unroll
    for (int s = 0; s < STEPS; s++) {
        if (s + 3 < STEPS) cb[(s+3)&3] = *(const half8*)(cp + (size_t)rowst*M*(s+3));
        half8 cv = cb[s&3];
        float tv[8]; float mx = -3.4e38f;
        #pragma unroll
        for (int k = 0; k < 8; k++) {
            float t = h[k] - (float)cv[k]*inv_eps;
            tv[k] = t; mx = fmaxf(mx, t);
        }
        #pragma unroll
        for (int o = W; o; o >>= 1) mx = fmaxf(mx, __shfl_xor(mx, o));
        float ft;
        if (!hard) {
            float sum = 0.f;
            #pragma unroll
            for (int k = 0; k < 8; k++) sum += exp2f((tv[k] - mx)*LOG2E);
            #pragma unroll
            for (int o = W; o; o >>= 1) sum += __shfl_xor(sum, o);
            ft = -eps*(mx + LN2*__log2f(sum));
        } else {
            ft = -eps*mx;                   // |err| <= eps*ln(M), negligible for eps<1e-5
        }
        if (wr) {
            int row = rr0 + rowst*s;
            fout[row] = fin ? ft : 0.5f*(fArr[s] + ft);
        }
    }
}

// ---------------- one eps-scaling iteration -------------------------------
// 2176 blocks, 8704 waves (7936 main @6KB + 768 tail @2KB), tails first so
// the 128 deferred blocks backfill behind them (cap = 8192 resident waves).
//  b <   64 : global tail   : matrix m=b,        rows [504,512), STEPS=2
//  b <  192 : local  tail   : matrix m=b-64,     rows [240,256), STEPS=2
//  b < 1536 : global main   : m=(b-192)/21, stripe r0=((b-192)%21)*24, STEPS=6
//  else     : local  main   : m=(b-1536)/5, stripe r0=((b-1536)%5)*48, STEPS=6
__global__ void __launch_bounds__(256) k_iter(float eps, float inv_eps, int par,
                                              int hard, int fin) {
    const float LGA = -5.545177444479562f;  // -ln 256
    const float LGG = -6.238324625039508f;  // -ln 512
    int b = blockIdx.x;
    int po = par, pn = par ^ 1;
    bool isG, tail; int m, r0;
    if (b < 64)        { isG = true;  tail = true;  m = b;        r0 = 504; }
    else if (b < 192)  { isG = false; tail = true;  m = b - 64;   r0 = 240; }
    else if (b < 1536) { int t = b - 192;  isG = true;  tail = false; m = t/21; r0 = (t%21)*24; }
    else               { int t = b - 1536; isG = false; tail = false; m = t/5;  r0 = (t%5)*48; }
    if (isG) {
        const _Float16* C = g_CG + (size_t)m*262144;
        const float *h, *fo; float* fn;
        if (m < 28)      { h = g_gG[po]+m*512;  fo = g_fG[po]+m*512;  fn = g_fG[pn]+m*512; }
        else if (m < 56) { int p = m-28;  h = g_fG[po]+p*512;  fo = g_gG[po]+p*512;  fn = g_gG[pn]+p*512; }
        else             { int c = m-56;  h = g_pxG[po]+c*512; fo = h;               fn = g_pxG[pn]+c*512; }
        if (tail) sm_pass<512,2>(C, h, fo, fn, r0, eps, inv_eps, LGG, hard, fin);
        else      sm_pass<512,6>(C, h, fo, fn, r0, eps, inv_eps, LGG, hard, fin);
    } else {
        const _Float16* C = g_CL + (size_t)m*65536;
        const float *h, *fo; float* fn;
        if (m < 56)       { h = g_gL[po]+m*256;  fo = g_fL[po]+m*256;  fn = g_fL[pn]+m*256; }
        else if (m < 112) { int p = m-56;  h = g_fL[po]+p*256;  fo = g_gL[po]+p*256;  fn = g_gL[pn]+p*256; }
        else              { int c = m-112; h = g_pxL[po]+c*256; fo = h;               fn = g_pxL[pn]+c*256; }
        if (tail) sm_pass<256,2>(C, h, fo, fn, r0, eps, inv_eps, LGA, hard, fin);
        else      sm_pass<256,6>(C, h, fo, fn, r0, eps, inv_eps, LGA, hard, fin);
    }
}

// ---------------- final reduction to the scalar loss ------------------------
__global__ void k_combine(float* __restrict__ out) {
    __shared__ float red[4][4];
    int tid = threadIdx.x;                  // 256 threads
    float sfg_l = 0.f, spx_l = 0.f, sfg_g = 0.f, spx_g = 0.f;
    for (int i = tid; i < 14336; i += 256) sfg_l += g_fL[1][i] + g_gL[1][i];
    for (int i = tid; i < 4096;  i += 256) spx_l += g_pxL[1][i];
    for (int i = tid; i < 14336; i += 256) sfg_g += g_fG[1][i] + g_gG[1][i];
    for (int i = tid; i < 4096;  i += 256) spx_g += g_pxG[1][i];
    for (int o = 32; o; o >>= 1) {
        sfg_l += __shfl_xor(sfg_l, o); spx_l += __shfl_xor(spx_l, o);
        sfg_g += __shfl_xor(sfg_g, o); spx_g += __shfl_xor(spx_g, o);
    }
    int w = tid >> 6;
    if ((tid & 63) == 0) { red[0][w] = sfg_l; red[1][w] = spx_l; red[2][w] = sfg_g; red[3][w] = spx_g; }
    __syncthreads();
    if (tid == 0) {
        float SL = red[0][0]+red[0][1]+red[0][2]+red[0][3];
        float PL = red[1][0]+red[1][1]+red[1][2]+red[1][3];
        float SG = red[2][0]+red[2][1]+red[2][2]+red[2][3];
        float PG = red[3][0]+red[3][1]+red[3][2]+red[3][3];
        float local_l  = SL/14336.f - PL/2048.f;
        float global_l = SG/14336.f - PG/2048.f;
        out[0] = 1.0f*local_l + 0.5f*global_l;
    }
}

// ---------------- host launcher ---------------------------------------------
extern "C" void kernel_launch(void* const* d_in, const int* in_sizes, int n_in,
                              void* d_out, int out_size, void* d_ws, size_t ws_size,
                              hipStream_t stream) {
    (void)in_sizes; (void)n_in; (void)out_size; (void)d_ws; (void)ws_size;
    const float* feat  = (const float*)d_in[0];
    const int* labels  = (const int*)d_in[1];
    const int* subg    = (const int*)d_in[2];

    k_index <<<24,    64, 0, stream>>>(labels, subg);
    k_gather<<<2048, 256, 0, stream>>>(feat);
    k_gemm  <<<24576,256, 0, stream>>>();
    k_init  <<<256,  256, 0, stream>>>();

    // eps schedule identical to reference (double, like numpy)
    double eps0 = 4.0*256.0, ratio = 0.9*0.9, target = 1e-4*1e-4;
    int n = (int)ceil(log(target/eps0)/log(ratio));    // 121 -> 122 iterations
    float ef = 1e-8f;
    for (int k = 0; k <= n; k++) {
        double e = eps0 * pow(ratio, (double)k);
        if (e < target) e = target;
        ef = (float)e;
        int hard = (ef < 1e-5f) ? 1 : 0;
        k_iter<<<2176, 256, 0, stream>>>(ef, (float)(1.0/(double)ef), k & 1, hard, 0);
    }
    // final extrapolation at eps_f (reads parity 0 carry, writes raw to parity 1)
    k_iter<<<2176, 256, 0, stream>>>(ef, (float)(1.0/(double)ef), 0, 1, 1);
    k_combine<<<1, 256, 0, stream>>>((float*)d_out);
}

// Round 12
// 1813.188 us; speedup vs baseline: 1.5909x; 1.0511x over previous
//
#include <hip/hip_runtime.h>
#include <math.h>

#define LOG2E 1.4426950408889634f
#define LN2   0.6931471805599453f

typedef short    short8  __attribute__((ext_vector_type(8)));
typedef float    floatx4 __attribute__((ext_vector_type(4)));
typedef _Float16 half8   __attribute__((ext_vector_type(8)));

__constant__ int c_pi[28] = {0,0,0,0,0,0,0,1,1,1,1,1,1,2,2,2,2,2,3,3,3,3,4,4,4,5,5,6};
__constant__ int c_pj[28] = {1,2,3,4,5,6,7,2,3,4,5,6,7,3,4,5,6,7,4,5,6,7,5,6,7,6,7,7};

// ---------------- static device storage ----------------
__device__ unsigned short g_cellsL[16*256*256];   // bf16 bits, gathered local cells
__device__ unsigned short g_cellsG[8*512*256];    // bf16 bits, gathered global cells
__device__ float g_x2L[16*256];
__device__ float g_x2G[8*512];
__device__ int   g_idxL[16*256];
__device__ int   g_idxG[8*512];
// fp16 cost matrices. Local: [0,56)=Cxy, [56,112)=Cyx(T), [112,128)=Cxx. 16.8 MB
// -> L3-resident (normal loads/stores).
__device__ _Float16 g_CL[128*256*256];
// Global: [0,28)=Cxy, [28,56)=Cyx(T), [56,64)=Cxx. 33.6 MB
// -> HBM-streamed (non-temporal stores in k_gemm, non-temporal loads in k_iter)
// so the L3 path (ceiling ~3.6 TB/s) and HBM path (~6.3 TB/s) run concurrently.
__device__ _Float16 g_CG[64*512*512];
__device__ float g_fL[2][56*256];
__device__ float g_gL[2][56*256];
__device__ float g_pxL[2][16*256];
__device__ float g_fG[2][28*512];
__device__ float g_gG[2][28*512];
__device__ float g_pxG[2][8*512];

// ---------------- helpers ----------------
__device__ __forceinline__ unsigned short f2bf(float f) {
    unsigned u = __float_as_uint(f);
    u += 0x7fffu + ((u >> 16) & 1u);          // RNE; inputs are finite
    return (unsigned short)(u >> 16);
}

// ---------------- index lists: first-m matches in order (ballot scan) -------
__global__ void k_index(const int* __restrict__ labels, const int* __restrict__ subg) {
    int b = blockIdx.x, lane = threadIdx.x;   // 24 blocks x 64 threads
    int want_l, want_s, cap; int* out;
    if (b < 16) { want_l = b >> 3; want_s = b & 7; cap = 256; out = g_idxL + b*256; }
    else        { want_l = -1;     want_s = b - 16; cap = 512; out = g_idxG + (b-16)*512; }
    int cnt = 0;
    for (int base = 0; base < 4096; base += 64) {
        int i = base + lane;
        bool m = (subg[i] == want_s) && (want_l < 0 || labels[i] == want_l);
        unsigned long long mask = __ballot(m);
        int pos = cnt + __popcll(mask & ((1ull << lane) - 1ull));
        if (m && pos < cap) out[pos] = i;
        cnt += __popcll(mask);
    }
}

// ---------------- gather rows -> bf16 cells + fp32 sq-norms -----------------
__global__ void k_gather(const float* __restrict__ feat) {
    int wv = blockIdx.x*4 + (threadIdx.x >> 6);   // 8192 waves, one row each
    int lane = threadIdx.x & 63;
    const float* src; unsigned short* dst; float* x2out;
    if (wv < 4096) {
        int c = wv >> 8, row = wv & 255;
        src = feat + (size_t)g_idxL[c*256+row]*256;
        dst = g_cellsL + (size_t)(c*256+row)*256;
        x2out = g_x2L + c*256 + row;
    } else {
        int v = wv - 4096; int c = v >> 9, row = v & 511;
        src = feat + (size_t)g_idxG[c*512+row]*256;
        dst = g_cellsG + (size_t)(c*512+row)*256;
        x2out = g_x2G + c*512 + row;
    }
    floatx4 v4 = *(const floatx4*)(src + lane*4);
    float s = v4[0]*v4[0] + v4[1]*v4[1] + v4[2]*v4[2] + v4[3]*v4[3];
    unsigned lo = (unsigned)f2bf(v4[0]) | ((unsigned)f2bf(v4[1]) << 16);
    unsigned hi = (unsigned)f2bf(v4[2]) | ((unsigned)f2bf(v4[3]) << 16);
    unsigned* d32 = (unsigned*)dst;
    d32[lane*2] = lo; d32[lane*2+1] = hi;
    for (int o = 32; o; o >>= 1) s += __shfl_xor(s, o);
    if (lane == 0) *x2out = s;
}

// ---------------- cost matrices via bf16 MFMA (wave = one 16x16 tile) -------
// C_ij = 0.5*max(x2_i + y2_j - 2*x.y, 0), stored fp16. T matrices are built as
// an independent GEMM with A/B swapped (coalesced writes, no transpose pass).
// Global matrices written non-temporally (no L3 allocation -> HBM only).
__global__ void k_gemm() {
    int job = blockIdx.x*4 + (threadIdx.x >> 6);
    int lane = threadIdx.x & 63;
    const unsigned short *A, *B; _Float16* Cout; const float *x2a, *x2b;
    int m, ti, tj;
    bool nt = (job >= 32768);
    if (job < 32768) {                      // local: 128 matrices x 256 tiles
        int mm = job >> 8, t = job & 255; ti = t >> 4; tj = t & 15; m = 256;
        int ca, cb;
        if (mm < 56)       { int lbl = mm/28,  q = mm%28;  ca = lbl*8 + c_pi[q]; cb = lbl*8 + c_pj[q]; }
        else if (mm < 112) { int p = mm-56; int lbl = p/28, q = p%28;
                             ca = lbl*8 + c_pj[q]; cb = lbl*8 + c_pi[q]; }
        else               { int c = mm-112; ca = cb = c; }
        A = g_cellsL + (size_t)ca*65536; B = g_cellsL + (size_t)cb*65536;
        x2a = g_x2L + ca*256; x2b = g_x2L + cb*256;
        Cout = g_CL + (size_t)mm*65536;
    } else {                                // global: 64 matrices x 1024 tiles
        int jj = job - 32768; int mm = jj >> 10, t = jj & 1023; ti = t >> 5; tj = t & 31; m = 512;
        int ca, cb;
        if (mm < 28)      { ca = c_pi[mm];    cb = c_pj[mm]; }
        else if (mm < 56) { ca = c_pj[mm-28]; cb = c_pi[mm-28]; }
        else              { ca = cb = mm-56; }
        A = g_cellsG + (size_t)ca*131072; B = g_cellsG + (size_t)cb*131072;
        x2a = g_x2G + ca*512; x2b = g_x2G + cb*512;
        Cout = g_CG + (size_t)mm*262144;
    }
    int r = lane & 15, quad = lane >> 4;
    const unsigned short* Ap = A + (size_t)(ti*16 + r)*256 + quad*8;
    const unsigned short* Bp = B + (size_t)(tj*16 + r)*256 + quad*8;
    floatx4 acc = {0.f, 0.f, 0.f, 0.f};
    #pragma unroll
    for (int k = 0; k < 256; k += 32) {
        short8 av = *(const short8*)(Ap + k);
        short8 bv = *(const short8*)(Bp + k);
        acc = __builtin_amdgcn_mfma_f32_16x16x32_bf16(av, bv, acc, 0, 0, 0);
    }
    int jc = tj*16 + r;                     // D: col = lane&15, row = quad*4 + reg
    float y2 = x2b[jc];
    #pragma unroll
    for (int rr = 0; rr < 4; rr++) {
        int ir = ti*16 + quad*4 + rr;
        float v = x2a[ir] + y2 - 2.f*acc[rr];
        _Float16 val = (_Float16)(0.5f*fmaxf(v, 0.f));
        if (nt) __builtin_nontemporal_store(val, &Cout[(size_t)ir*m + jc]);
        else    Cout[(size_t)ir*m + jc] = val;
    }
}

// ---------------- zero the parity-0 potential buffers -----------------------
__global__ void k_init() {
    int t = blockIdx.x*256 + threadIdx.x;   // 65536 threads
    if      (t < 14336) g_fL[0][t] = 0.f;
    else if (t < 28672) g_gL[0][t-14336] = 0.f;
    else if (t < 32768) g_pxL[0][t-28672] = 0.f;
    else if (t < 47104) g_fG[0][t-32768] = 0.f;
    else if (t < 61440) g_gG[0][t-47104] = 0.f;
    else                g_pxG[0][t-61440] = 0.f;
}

// ---------------- row softmin pass, fully register-resident -----------------
// ft_i = -eps*LSE_j(h_j - C_ij/eps); every pass is a row pass (T materialized).
// M=256: half-wave per row (lanes 0-31 / 32-63), 2*STEPS rows/wave.
// M=512: full wave per row, STEPS rows/wave.
// STEPS=6 main stripes (6 KB/wave), STEPS=2 tail stripes (2 KB/wave).
// 4-deep C prefetch ring + upfront f_old preload. NT=1: non-temporal C loads
// (global matrices stream from HBM, bypassing the ~3.6 TB/s L3 fill path).
template<int M, int STEPS, int NT>
__device__ __forceinline__ void sm_pass(const _Float16* __restrict__ C,
    const float* __restrict__ hsrc, const float* __restrict__ fold,
    float* __restrict__ fout, int r0, float eps, float inv_eps, float loga,
    int hard, int fin)
{
    const int W = (M == 256) ? 16 : 32;     // shfl butterfly start
    int tid = threadIdx.x, lane = tid & 63, w = tid >> 6;
    int co = (M == 256) ? (lane & 31) : lane;
    float h[8];
    floatx4 h0 = *(const floatx4*)(hsrc + co*8);
    floatx4 h1 = *(const floatx4*)(hsrc + co*8 + 4);
    #pragma unroll
    for (int k = 0; k < 4; k++) { h[k] = loga + h0[k]*inv_eps; h[4+k] = loga + h1[k]*inv_eps; }
    int rbase = (M == 256) ? (r0 + w*2*STEPS) : (r0 + w*STEPS);
    int rowst = (M == 256) ? 2 : 1;
    int radd  = (M == 256) ? (lane >> 5) : 0;
    bool wr   = (M == 256) ? ((lane & 31) == 0) : (lane == 0);
    int rr0 = rbase + radd;

    const _Float16* cp = C + (size_t)rr0*M + co*8;
    float fArr[STEPS];
    #pragma unroll
    for (int s = 0; s < STEPS; s++) fArr[s] = fold[rr0 + rowst*s];
    half8 cb[4];
    #pragma unroll
    for (int s = 0; s < 3; s++)
        if (s < STEPS) {
            const half8* p = (const half8*)(cp + (size_t)rowst*M*s);
            cb[s] = NT ? __builtin_nontemporal_load(p) : *p;
        }
    #pragma unroll
    for (int s = 0; s < STEPS; s++) {
        if (s + 3 < STEPS) {
            const half8* p = (const half8*)(cp + (size_t)rowst*M*(s+3));
            cb[(s+3)&3] = NT ? __builtin_nontemporal_load(p) : *p;
        }
        half8 cv = cb[s&3];
        float tv[8]; float mx = -3.4e38f;
        #pragma unroll
        for (int k = 0; k < 8; k++) {
            float t = h[k] - (float)cv[k]*inv_eps;
            tv[k] = t; mx = fmaxf(mx, t);
        }
        #pragma unroll
        for (int o = W; o; o >>= 1) mx = fmaxf(mx, __shfl_xor(mx, o));
        float ft;
        if (!hard) {
            float sum = 0.f;
            #pragma unroll
            for (int k = 0; k < 8; k++) sum += exp2f((tv[k] - mx)*LOG2E);
            #pragma unroll
            for (int o = W; o; o >>= 1) sum += __shfl_xor(sum, o);
            ft = -eps*(mx + LN2*__log2f(sum));
        } else {
            ft = -eps*mx;                   // |err| <= eps*ln(M), negligible for eps<1e-5
        }
        if (wr) {
            int row = rr0 + rowst*s;
            fout[row] = fin ? ft : 0.5f*(fArr[s] + ft);
        }
    }
}

// ---------------- one eps-scaling iteration -------------------------------
// 2176 blocks, 8704 waves (7936 main @6KB + 768 tail @2KB), tails first so
// the 128 deferred blocks backfill behind them (cap = 8192 resident waves).
//  b <   64 : global tail   : matrix m=b,        rows [504,512), STEPS=2
//  b <  192 : local  tail   : matrix m=b-64,     rows [240,256), STEPS=2
//  b < 1536 : global main   : m=(b-192)/21, stripe r0=((b-192)%21)*24, STEPS=6
//  else     : local  main   : m=(b-1536)/5, stripe r0=((b-1536)%5)*48, STEPS=6
__global__ void __launch_bounds__(256) k_iter(float eps, float inv_eps, int par,
                                              int hard, int fin) {
    const float LGA = -5.545177444479562f;  // -ln 256
    const float LGG = -6.238324625039508f;  // -ln 512
    int b = blockIdx.x;
    int po = par, pn = par ^ 1;
    bool isG, tail; int m, r0;
    if (b < 64)        { isG = true;  tail = true;  m = b;        r0 = 504; }
    else if (b < 192)  { isG = false; tail = true;  m = b - 64;   r0 = 240; }
    else if (b < 1536) { int t = b - 192;  isG = true;  tail = false; m = t/21; r0 = (t%21)*24; }
    else               { int t = b - 1536; isG = false; tail = false; m = t/5;  r0 = (t%5)*48; }
    if (isG) {
        const _Float16* C = g_CG + (size_t)m*262144;
        const float *h, *fo; float* fn;
        if (m < 28)      { h = g_gG[po]+m*512;  fo = g_fG[po]+m*512;  fn = g_fG[pn]+m*512; }
        else if (m < 56) { int p = m-28;  h = g_fG[po]+p*512;  fo = g_gG[po]+p*512;  fn = g_gG[pn]+p*512; }
        else             { int c = m-56;  h = g_pxG[po]+c*512; fo = h;               fn = g_pxG[pn]+c*512; }
        if (tail) sm_pass<512,2,1>(C, h, fo, fn, r0, eps, inv_eps, LGG, hard, fin);
        else      sm_pass<512,6,1>(C, h, fo, fn, r0, eps, inv_eps, LGG, hard, fin);
    } else {
        const _Float16* C = g_CL + (size_t)m*65536;
        const float *h, *fo; float* fn;
        if (m < 56)       { h = g_gL[po]+m*256;  fo = g_fL[po]+m*256;  fn = g_fL[pn]+m*256; }
        else if (m < 112) { int p = m-56;  h = g_fL[po]+p*256;  fo = g_gL[po]+p*256;  fn = g_gL[pn]+p*256; }
        else              { int c = m-112; h = g_pxL[po]+c*256; fo = h;               fn = g_pxL[pn]+c*256; }
        if (tail) sm_pass<256,2,0>(C, h, fo, fn, r0, eps, inv_eps, LGA, hard, fin);
        else      sm_pass<256,6,0>(C, h, fo, fn, r0, eps, inv_eps, LGA, hard, fin);
    }
}

// ---------------- final reduction to the scalar loss ------------------------
__global__ void k_combine(float* __restrict__ out) {
    __shared__ float red[4][4];
    int tid = threadIdx.x;                  // 256 threads
    float sfg_l = 0.f, spx_l = 0.f, sfg_g = 0.f, spx_g = 0.f;
    for (int i = tid; i < 14336; i += 256) sfg_l += g_fL[1][i] + g_gL[1][i];
    for (int i = tid; i < 4096;  i += 256) spx_l += g_pxL[1][i];
    for (int i = tid; i < 14336; i += 256) sfg_g += g_fG[1][i] + g_gG[1][i];
    for (int i = tid; i < 4096;  i += 256) spx_g += g_pxG[1][i];
    for (int o = 32; o; o >>= 1) {
        sfg_l += __shfl_xor(sfg_l, o); spx_l += __shfl_xor(spx_l, o);
        sfg_g += __shfl_xor(sfg_g, o); spx_g += __shfl_xor(spx_g, o);
    }
    int w = tid >> 6;
    if ((tid & 63) == 0) { red[0][w] = sfg_l; red[1][w] = spx_l; red[2][w] = sfg_g; red[3][w] = spx_g; }
    __syncthreads();
    if (tid == 0) {
        float SL = red[0][0]+red[0][1]+red[0][2]+red[0][3];
        float PL = red[1][0]+red[1][1]+red[1][2]+red[1][3];
        float SG = red[2][0]+red[2][1]+red[2][2]+red[2][3];
        float PG = red[3][0]+red[3][1]+red[3][2]+red[3][3];
        float local_l  = SL/14336.f - PL/2048.f;
        float global_l = SG/14336.f - PG/2048.f;
        out[0] = 1.0f*local_l + 0.5f*global_l;
    }
}

// ---------------- host launcher ---------------------------------------------
extern "C" void kernel_launch(void* const* d_in, const int* in_sizes, int n_in,
                              void* d_out, int out_size, void* d_ws, size_t ws_size,
                              hipStream_t stream) {
    (void)in_sizes; (void)n_in; (void)out_size; (void)d_ws; (void)ws_size;
    const float* feat  = (const float*)d_in[0];
    const int* labels  = (const int*)d_in[1];
    const int* subg    = (const int*)d_in[2];

    k_index <<<24,    64, 0, stream>>>(labels, subg);
    k_gather<<<2048, 256, 0, stream>>>(feat);
    k_gemm  <<<24576,256, 0, stream>>>();
    k_init  <<<256,  256, 0, stream>>>();

    // eps schedule identical to reference (double, like numpy)
    double eps0 = 4.0*256.0, ratio = 0.9*0.9, target = 1e-4*1e-4;
    int n = (int)ceil(log(target/eps0)/log(ratio));    // 121 -> 122 iterations
    float ef = 1e-8f;
    for (int k = 0; k <= n; k++) {
        double e = eps0 * pow(ratio, (double)k);
        if (e < target) e = target;
        ef = (float)e;
        int hard = (ef < 1e-5f) ? 1 : 0;
        k_iter<<<2176, 256, 0, stream>>>(ef, (float)(1.0/(double)ef), k & 1, hard, 0);
    }
    // final extrapolation at eps_f (reads parity 0 carry, writes raw to parity 1)
    k_iter<<<2176, 256, 0, stream>>>(ef, (float)(1.0/(double)ef), 0, 1, 1);
    k_combine<<<1, 256, 0, stream>>>((float*)d_out);
}

// Round 13
// 1782.188 us; speedup vs baseline: 1.6186x; 1.0174x over previous
//
#include <hip/hip_runtime.h>
#include <math.h>

#define LOG2E 1.4426950408889634f
#define LN2   0.6931471805599453f

typedef short    short8  __attribute__((ext_vector_type(8)));
typedef float    floatx4 __attribute__((ext_vector_type(4)));
typedef _Float16 half8   __attribute__((ext_vector_type(8)));

__constant__ int c_pi[28] = {0,0,0,0,0,0,0,1,1,1,1,1,1,2,2,2,2,2,3,3,3,3,4,4,4,5,5,6};
__constant__ int c_pj[28] = {1,2,3,4,5,6,7,2,3,4,5,6,7,3,4,5,6,7,4,5,6,7,5,6,7,6,7,7};

// ---------------- static device storage ----------------
__device__ unsigned short g_cellsL[16*256*256];   // bf16 bits, gathered local cells
__device__ unsigned short g_cellsG[8*512*256];    // bf16 bits, gathered global cells
__device__ float g_x2L[16*256];
__device__ float g_x2G[8*512];
__device__ int   g_idxL[16*256];
__device__ int   g_idxG[8*512];
// fp16 cost matrices. Local: [0,56)=Cxy, [56,112)=Cyx(T), [112,128)=Cxx. 16.8 MB
__device__ _Float16 g_CL[128*256*256];
// Global: [0,28)=Cxy, [28,56)=Cyx(T), [56,64)=Cxx. 33.6 MB
// ALL C is written with non-temporal stores and read with non-temporal loads:
// within a k_iter launch every byte is read exactly once, and the dispatch
// boundary invalidates L2 -> cache allocation buys nothing; stream via HBM.
__device__ _Float16 g_CG[64*512*512];
__device__ float g_fL[2][56*256];
__device__ float g_gL[2][56*256];
__device__ float g_pxL[2][16*256];
__device__ float g_fG[2][28*512];
__device__ float g_gG[2][28*512];
__device__ float g_pxG[2][8*512];

// ---------------- helpers ----------------
__device__ __forceinline__ unsigned short f2bf(float f) {
    unsigned u = __float_as_uint(f);
    u += 0x7fffu + ((u >> 16) & 1u);          // RNE; inputs are finite
    return (unsigned short)(u >> 16);
}

// ---------------- index lists: first-m matches in order (ballot scan) -------
__global__ void k_index(const int* __restrict__ labels, const int* __restrict__ subg) {
    int b = blockIdx.x, lane = threadIdx.x;   // 24 blocks x 64 threads
    int want_l, want_s, cap; int* out;
    if (b < 16) { want_l = b >> 3; want_s = b & 7; cap = 256; out = g_idxL + b*256; }
    else        { want_l = -1;     want_s = b - 16; cap = 512; out = g_idxG + (b-16)*512; }
    int cnt = 0;
    for (int base = 0; base < 4096; base += 64) {
        int i = base + lane;
        bool m = (subg[i] == want_s) && (want_l < 0 || labels[i] == want_l);
        unsigned long long mask = __ballot(m);
        int pos = cnt + __popcll(mask & ((1ull << lane) - 1ull));
        if (m && pos < cap) out[pos] = i;
        cnt += __popcll(mask);
    }
}

// ---------------- gather rows -> bf16 cells + fp32 sq-norms -----------------
__global__ void k_gather(const float* __restrict__ feat) {
    int wv = blockIdx.x*4 + (threadIdx.x >> 6);   // 8192 waves, one row each
    int lane = threadIdx.x & 63;
    const float* src; unsigned short* dst; float* x2out;
    if (wv < 4096) {
        int c = wv >> 8, row = wv & 255;
        src = feat + (size_t)g_idxL[c*256+row]*256;
        dst = g_cellsL + (size_t)(c*256+row)*256;
        x2out = g_x2L + c*256 + row;
    } else {
        int v = wv - 4096; int c = v >> 9, row = v & 511;
        src = feat + (size_t)g_idxG[c*512+row]*256;
        dst = g_cellsG + (size_t)(c*512+row)*256;
        x2out = g_x2G + c*512 + row;
    }
    floatx4 v4 = *(const floatx4*)(src + lane*4);
    float s = v4[0]*v4[0] + v4[1]*v4[1] + v4[2]*v4[2] + v4[3]*v4[3];
    unsigned lo = (unsigned)f2bf(v4[0]) | ((unsigned)f2bf(v4[1]) << 16);
    unsigned hi = (unsigned)f2bf(v4[2]) | ((unsigned)f2bf(v4[3]) << 16);
    unsigned* d32 = (unsigned*)dst;
    d32[lane*2] = lo; d32[lane*2+1] = hi;
    for (int o = 32; o; o >>= 1) s += __shfl_xor(s, o);
    if (lane == 0) *x2out = s;
}

// ---------------- cost matrices via bf16 MFMA (wave = 16x64 output tile) ----
// C_ij = 0.5*max(x2_i + y2_j - 2*x.y, 0), stored fp16 (non-temporal).
// 4 tj-tiles share one A fragment: 5 loads + 4 MFMAs per k-step (was 8 loads
// + 4 MFMAs across 4 independent jobs) -> 37.5% fewer load instrs, r12's
// k_gemm was load-latency-bound (MfmaUtil 2.7%, VGPR 32).
__global__ void k_gemm() {
    int job = blockIdx.x*4 + (threadIdx.x >> 6);   // 6144 blocks -> 24576 jobs
    int lane = threadIdx.x & 63;
    const unsigned short *A, *B; _Float16* Cout; const float *x2a, *x2b;
    int m, ti, tjq;
    if (job < 8192) {                       // local: 128 matrices x 64 jobs (16x4)
        int mm = job >> 6, t = job & 63; ti = t >> 2; tjq = t & 3; m = 256;
        int ca, cb;
        if (mm < 56)       { int lbl = mm/28,  q = mm%28;  ca = lbl*8 + c_pi[q]; cb = lbl*8 + c_pj[q]; }
        else if (mm < 112) { int p = mm-56; int lbl = p/28, q = p%28;
                             ca = lbl*8 + c_pj[q]; cb = lbl*8 + c_pi[q]; }
        else               { int c = mm-112; ca = cb = c; }
        A = g_cellsL + (size_t)ca*65536; B = g_cellsL + (size_t)cb*65536;
        x2a = g_x2L + ca*256; x2b = g_x2L + cb*256;
        Cout = g_CL + (size_t)mm*65536;
    } else {                                // global: 64 matrices x 256 jobs (32x8)
        int jj = job - 8192; int mm = jj >> 8, t = jj & 255; ti = t >> 3; tjq = t & 7; m = 512;
        int ca, cb;
        if (mm < 28)      { ca = c_pi[mm];    cb = c_pj[mm]; }
        else if (mm < 56) { ca = c_pj[mm-28]; cb = c_pi[mm-28]; }
        else              { ca = cb = mm-56; }
        A = g_cellsG + (size_t)ca*131072; B = g_cellsG + (size_t)cb*131072;
        x2a = g_x2G + ca*512; x2b = g_x2G + cb*512;
        Cout = g_CG + (size_t)mm*262144;
    }
    int r = lane & 15, quad = lane >> 4;
    const unsigned short* Ap = A + (size_t)(ti*16 + r)*256 + quad*8;
    const unsigned short* Bp = B + (size_t)(tjq*64 + r)*256 + quad*8;
    floatx4 acc0 = {0.f,0.f,0.f,0.f}, acc1 = {0.f,0.f,0.f,0.f};
    floatx4 acc2 = {0.f,0.f,0.f,0.f}, acc3 = {0.f,0.f,0.f,0.f};
    #pragma unroll
    for (int k = 0; k < 256; k += 32) {
        short8 av  = *(const short8*)(Ap + k);
        short8 bv0 = *(const short8*)(Bp + k);
        short8 bv1 = *(const short8*)(Bp + (size_t)16*256 + k);
        short8 bv2 = *(const short8*)(Bp + (size_t)32*256 + k);
        short8 bv3 = *(const short8*)(Bp + (size_t)48*256 + k);
        acc0 = __builtin_amdgcn_mfma_f32_16x16x32_bf16(av, bv0, acc0, 0, 0, 0);
        acc1 = __builtin_amdgcn_mfma_f32_16x16x32_bf16(av, bv1, acc1, 0, 0, 0);
        acc2 = __builtin_amdgcn_mfma_f32_16x16x32_bf16(av, bv2, acc2, 0, 0, 0);
        acc3 = __builtin_amdgcn_mfma_f32_16x16x32_bf16(av, bv3, acc3, 0, 0, 0);
    }
    float accs[4][4] = {
        {acc0[0],acc0[1],acc0[2],acc0[3]}, {acc1[0],acc1[1],acc1[2],acc1[3]},
        {acc2[0],acc2[1],acc2[2],acc2[3]}, {acc3[0],acc3[1],acc3[2],acc3[3]} };
    #pragma unroll
    for (int n = 0; n < 4; n++) {
        int jc = tjq*64 + n*16 + r;         // D: col = lane&15, row = quad*4 + reg
        float y2 = x2b[jc];
        #pragma unroll
        for (int rr = 0; rr < 4; rr++) {
            int ir = ti*16 + quad*4 + rr;
            float v = x2a[ir] + y2 - 2.f*accs[n][rr];
            _Float16 val = (_Float16)(0.5f*fmaxf(v, 0.f));
            __builtin_nontemporal_store(val, &Cout[(size_t)ir*m + jc]);
        }
    }
}

// ---------------- zero the parity-0 potential buffers -----------------------
__global__ void k_init() {
    int t = blockIdx.x*256 + threadIdx.x;   // 65536 threads
    if      (t < 14336) g_fL[0][t] = 0.f;
    else if (t < 28672) g_gL[0][t-14336] = 0.f;
    else if (t < 32768) g_pxL[0][t-28672] = 0.f;
    else if (t < 47104) g_fG[0][t-32768] = 0.f;
    else if (t < 61440) g_gG[0][t-47104] = 0.f;
    else                g_pxG[0][t-61440] = 0.f;
}

// ---------------- row softmin pass, fully register-resident -----------------
// ft_i = -eps*LSE_j(h_j - C_ij/eps); every pass is a row pass (T materialized).
// M=256: half-wave per row (lanes 0-31 / 32-63), 2*STEPS rows/wave.
// M=512: full wave per row, STEPS rows/wave.
// STEPS=6 main stripes (6 KB/wave), STEPS=2 tail stripes (2 KB/wave).
// 4-deep C prefetch ring + upfront f_old preload; all C loads non-temporal.
template<int M, int STEPS>
__device__ __forceinline__ void sm_pass(const _Float16* __restrict__ C,
    const float* __restrict__ hsrc, const float* __restrict__ fold,
    float* __restrict__ fout, int r0, float eps, float inv_eps, float loga,
    int hard, int fin)
{
    const int W = (M == 256) ? 16 : 32;     // shfl butterfly start
    int tid = threadIdx.x, lane = tid & 63, w = tid >> 6;
    int co = (M == 256) ? (lane & 31) : lane;
    float h[8];
    floatx4 h0 = *(const floatx4*)(hsrc + co*8);
    floatx4 h1 = *(const floatx4*)(hsrc + co*8 + 4);
    #pragma unroll
    for (int k = 0; k < 4; k++) { h[k] = loga + h0[k]*inv_eps; h[4+k] = loga + h1[k]*inv_eps; }
    int rbase = (M == 256) ? (r0 + w*2*STEPS) : (r0 + w*STEPS);
    int rowst = (M == 256) ? 2 : 1;
    int radd  = (M == 256) ? (lane >> 5) : 0;
    bool wr   = (M == 256) ? ((lane & 31) == 0) : (lane == 0);
    int rr0 = rbase + radd;

    const _Float16* cp = C + (size_t)rr0*M + co*8;
    float fArr[STEPS];
    #pragma unroll
    for (int s = 0; s < STEPS; s++) fArr[s] = fold[rr0 + rowst*s];
    half8 cb[4];
    #pragma unroll
    for (int s = 0; s < 3; s++)
        if (s < STEPS)
            cb[s] = __builtin_nontemporal_load((const half8*)(cp + (size_t)rowst*M*s));
    #pragma unroll
    for (int s = 0; s < STEPS; s++) {
        if (s + 3 < STEPS)
            cb[(s+3)&3] = __builtin_nontemporal_load((const half8*)(cp + (size_t)rowst*M*(s+3)));
        half8 cv = cb[s&3];
        float tv[8]; float mx = -3.4e38f;
        #pragma unroll
        for (int k = 0; k < 8; k++) {
            float t = h[k] - (float)cv[k]*inv_eps;
            tv[k] = t; mx = fmaxf(mx, t);
        }
        #pragma unroll
        for (int o = W; o; o >>= 1) mx = fmaxf(mx, __shfl_xor(mx, o));
        float ft;
        if (!hard) {
            float sum = 0.f;
            #pragma unroll
            for (int k = 0; k < 8; k++) sum += exp2f((tv[k] - mx)*LOG2E);
            #pragma unroll
            for (int o = W; o; o >>= 1) sum += __shfl_xor(sum, o);
            ft = -eps*(mx + LN2*__log2f(sum));
        } else {
            ft = -eps*mx;                   // |err| <= eps*ln(M), negligible for eps<1e-5
        }
        if (wr) {
            int row = rr0 + rowst*s;
            fout[row] = fin ? ft : 0.5f*(fArr[s] + ft);
        }
    }
}

// ---------------- one eps-scaling iteration -------------------------------
// 2176 blocks, 8704 waves (7936 main @6KB + 768 tail @2KB), tails first so
// the 128 deferred blocks backfill behind them (cap = 8192 resident waves).
//  b <   64 : global tail   : matrix m=b,        rows [504,512), STEPS=2
//  b <  192 : local  tail   : matrix m=b-64,     rows [240,256), STEPS=2
//  b < 1536 : global main   : m=(b-192)/21, stripe r0=((b-192)%21)*24, STEPS=6
//  else     : local  main   : m=(b-1536)/5, stripe r0=((b-1536)%5)*48, STEPS=6
__global__ void __launch_bounds__(256) k_iter(float eps, float inv_eps, int par,
                                              int hard, int fin) {
    const float LGA = -5.545177444479562f;  // -ln 256
    const float LGG = -6.238324625039508f;  // -ln 512
    int b = blockIdx.x;
    int po = par, pn = par ^ 1;
    bool isG, tail; int m, r0;
    if (b < 64)        { isG = true;  tail = true;  m = b;        r0 = 504; }
    else if (b < 192)  { isG = false; tail = true;  m = b - 64;   r0 = 240; }
    else if (b < 1536) { int t = b - 192;  isG = true;  tail = false; m = t/21; r0 = (t%21)*24; }
    else               { int t = b - 1536; isG = false; tail = false; m = t/5;  r0 = (t%5)*48; }
    if (isG) {
        const _Float16* C = g_CG + (size_t)m*262144;
        const float *h, *fo; float* fn;
        if (m < 28)      { h = g_gG[po]+m*512;  fo = g_fG[po]+m*512;  fn = g_fG[pn]+m*512; }
        else if (m < 56) { int p = m-28;  h = g_fG[po]+p*512;  fo = g_gG[po]+p*512;  fn = g_gG[pn]+p*512; }
        else             { int c = m-56;  h = g_pxG[po]+c*512; fo = h;               fn = g_pxG[pn]+c*512; }
        if (tail) sm_pass<512,2>(C, h, fo, fn, r0, eps, inv_eps, LGG, hard, fin);
        else      sm_pass<512,6>(C, h, fo, fn, r0, eps, inv_eps, LGG, hard, fin);
    } else {
        const _Float16* C = g_CL + (size_t)m*65536;
        const float *h, *fo; float* fn;
        if (m < 56)       { h = g_gL[po]+m*256;  fo = g_fL[po]+m*256;  fn = g_fL[pn]+m*256; }
        else if (m < 112) { int p = m-56;  h = g_fL[po]+p*256;  fo = g_gL[po]+p*256;  fn = g_gL[pn]+p*256; }
        else              { int c = m-112; h = g_pxL[po]+c*256; fo = h;               fn = g_pxL[pn]+c*256; }
        if (tail) sm_pass<256,2>(C, h, fo, fn, r0, eps, inv_eps, LGA, hard, fin);
        else      sm_pass<256,6>(C, h, fo, fn, r0, eps, inv_eps, LGA, hard, fin);
    }
}

// ---------------- final reduction to the scalar loss ------------------------
__global__ void k_combine(float* __restrict__ out) {
    __shared__ float red[4][4];
    int tid = threadIdx.x;                  // 256 threads
    float sfg_l = 0.f, spx_l = 0.f, sfg_g = 0.f, spx_g = 0.f;
    for (int i = tid; i < 14336; i += 256) sfg_l += g_fL[1][i] + g_gL[1][i];
    for (int i = tid; i < 4096;  i += 256) spx_l += g_pxL[1][i];
    for (int i = tid; i < 14336; i += 256) sfg_g += g_fG[1][i] + g_gG[1][i];
    for (int i = tid; i < 4096;  i += 256) spx_g += g_pxG[1][i];
    for (int o = 32; o; o >>= 1) {
        sfg_l += __shfl_xor(sfg_l, o); spx_l += __shfl_xor(spx_l, o);
        sfg_g += __shfl_xor(sfg_g, o); spx_g += __shfl_xor(spx_g, o);
    }
    int w = tid >> 6;
    if ((tid & 63) == 0) { red[0][w] = sfg_l; red[1][w] = spx_l; red[2][w] = sfg_g; red[3][w] = spx_g; }
    __syncthreads();
    if (tid == 0) {
        float SL = red[0][0]+red[0][1]+red[0][2]+red[0][3];
        float PL = red[1][0]+red[1][1]+red[1][2]+red[1][3];
        float SG = red[2][0]+red[2][1]+red[2][2]+red[2][3];
        float PG = red[3][0]+red[3][1]+red[3][2]+red[3][3];
        float local_l  = SL/14336.f - PL/2048.f;
        float global_l = SG/14336.f - PG/2048.f;
        out[0] = 1.0f*local_l + 0.5f*global_l;
    }
}

// ---------------- host launcher ---------------------------------------------
extern "C" void kernel_launch(void* const* d_in, const int* in_sizes, int n_in,
                              void* d_out, int out_size, void* d_ws, size_t ws_size,
                              hipStream_t stream) {
    (void)in_sizes; (void)n_in; (void)out_size; (void)d_ws; (void)ws_size;
    const float* feat  = (const float*)d_in[0];
    const int* labels  = (const int*)d_in[1];
    const int* subg    = (const int*)d_in[2];

    k_index <<<24,    64, 0, stream>>>(labels, subg);
    k_gather<<<2048, 256, 0, stream>>>(feat);
    k_gemm  <<<6144, 256, 0, stream>>>();   // 24576 jobs (16x64 tiles), 4/block
    k_init  <<<256,  256, 0, stream>>>();

    // eps schedule identical to reference (double, like numpy)
    double eps0 = 4.0*256.0, ratio = 0.9*0.9, target = 1e-4*1e-4;
    int n = (int)ceil(log(target/eps0)/log(ratio));    // 121 -> 122 iterations
    float ef = 1e-8f;
    for (int k = 0; k <= n; k++) {
        double e = eps0 * pow(ratio, (double)k);
        if (e < target) e = target;
        ef = (float)e;
        int hard = (ef < 1e-5f) ? 1 : 0;
        k_iter<<<2176, 256, 0, stream>>>(ef, (float)(1.0/(double)ef), k & 1, hard, 0);
    }
    // final extrapolation at eps_f (reads parity 0 carry, writes raw to parity 1)
    k_iter<<<2176, 256, 0, stream>>>(ef, (float)(1.0/(double)ef), 0, 1, 1);
    k_combine<<<1, 256, 0, stream>>>((float*)d_out);
}